// Round 7
// baseline (56.787 us; speedup 1.0000x reference)
//
#include <hip/hip_runtime.h>
#include <math.h>

// Problem: x is (64, 1048576) f32 = 64M elements. Reference returns True
// iff argmax-with-lowest-index-ties != argmax-with-highest-index-ties, i.e.
// iff the global maximum value occurs at more than one index.
// Output dtype is bool -> harness reads d_out as int32. Store int 0/1.
//
// Journal: R2 two-kernel grid-stride float4 = 49.35us. R4 fused same-line
// atomics = 121us (serialized RMW tail). R5 4x pow2-strided unroll = 55.9us
// (channel aliasing). R6 wave-shuffle reduce + 16B partials = 49.17us (best).
// R7 (this): nontemporal loads (pure stream, zero reuse -> skip L2 allocate)
// + 2 contiguous float4 per thread per iter (32B/thread, halved loop count,
// 2 loads in flight, no pow2 long-stride aliasing).

#define NB 2048   // blocks; 8 blocks/CU on 256 CUs = 32 waves/CU
#define NT 256    // threads per block (4 waves)

typedef float f32x4 __attribute__((ext_vector_type(4)));

struct Trip16 { float v; int imin; int imax; int pad; };  // 16B for dwordx4

__device__ __forceinline__ void upd(float x, int idx, float& v, int& imin, int& imax) {
    if (x > v)      { v = x; imin = idx; imax = idx; }
    else if (x == v){ if (idx < imin) imin = idx; if (idx > imax) imax = idx; }
}

__device__ __forceinline__ void upd4(const f32x4& f, int b, float& v, int& imin, int& imax) {
    upd(f[0], b,     v, imin, imax);
    upd(f[1], b + 1, v, imin, imax);
    upd(f[2], b + 2, v, imin, imax);
    upd(f[3], b + 3, v, imin, imax);
}

__device__ __forceinline__ void merge(float bv, int bmn, int bmx,
                                      float& v, int& imin, int& imax) {
    if (bv > v)       { v = bv; imin = bmn; imax = bmx; }
    else if (bv == v) { if (bmn < imin) imin = bmn; if (bmx > imax) imax = bmx; }
}

// 64-lane butterfly reduce of (v, imin, imax) — register-only.
__device__ __forceinline__ void wave_reduce(float& v, int& imin, int& imax) {
    #pragma unroll
    for (int m = 32; m > 0; m >>= 1) {
        float ov = __shfl_xor(v, m, 64);
        int omn   = __shfl_xor(imin, m, 64);
        int omx   = __shfl_xor(imax, m, 64);
        merge(ov, omn, omx, v, imin, imax);
    }
}

__global__ __launch_bounds__(NT) void argmax_part(const f32x4* __restrict__ x,
                                                  Trip16* __restrict__ part, int n4) {
    const int tid = blockIdx.x * NT + threadIdx.x;
    const int stride = NB * NT;
    float v = -INFINITY; int imin = 0x7fffffff, imax = -1;

    const int n8 = n4 >> 1;   // pairs of float4
    // Each thread reads 32B contiguous (two float4) per iteration.
    for (int i = tid; i < n8; i += stride) {
        f32x4 a = __builtin_nontemporal_load(&x[2 * i]);
        f32x4 b = __builtin_nontemporal_load(&x[2 * i + 1]);
        upd4(a, (2 * i) << 2,     v, imin, imax);
        upd4(b, (2 * i + 1) << 2, v, imin, imax);
    }
    // Leftover float4 (n4 odd) + scalar tail — none for this shape, but be safe.
    if (blockIdx.x == 0) {
        if (n4 & 1) {
            // one leftover float4 at index n4-1, handled by thread 0
            if (threadIdx.x == 0) {
                f32x4 f = x[n4 - 1];
                upd4(f, (n4 - 1) << 2, v, imin, imax);
            }
        }
    }

    wave_reduce(v, imin, imax);

    __shared__ float sv[NT / 64];
    __shared__ int   smn[NT / 64], smx[NT / 64];
    const int lane = threadIdx.x & 63;
    const int wid  = threadIdx.x >> 6;
    if (lane == 0) { sv[wid] = v; smn[wid] = imin; smx[wid] = imax; }
    __syncthreads();
    if (threadIdx.x == 0) {
        #pragma unroll
        for (int w = 1; w < NT / 64; ++w) merge(sv[w], smn[w], smx[w], v, imin, imax);
        f32x4 p;
        p[0] = v; p[1] = __int_as_float(imin); p[2] = __int_as_float(imax); p[3] = 0.0f;
        *reinterpret_cast<f32x4*>(&part[blockIdx.x]) = p;
    }
}

__global__ __launch_bounds__(NT) void argmax_final(const f32x4* __restrict__ part,
                                                   const float* __restrict__ x,
                                                   int n4, int n,
                                                   int* __restrict__ out) {
    const int t = threadIdx.x;
    float v = -INFINITY; int imin = 0x7fffffff, imax = -1;
    #pragma unroll
    for (int k = 0; k < NB / NT; ++k) {
        f32x4 p = part[t + k * NT];
        merge(p[0], __float_as_int(p[1]), __float_as_int(p[2]), v, imin, imax);
    }
    // Scalar tail (n not divisible by 4) — none for this shape, but be safe.
    for (int i = n4 * 4 + t; i < n; i += NT) upd(x[i], i, v, imin, imax);

    wave_reduce(v, imin, imax);

    __shared__ float sv[NT / 64];
    __shared__ int   smn[NT / 64], smx[NT / 64];
    const int lane = t & 63;
    const int wid  = t >> 6;
    if (lane == 0) { sv[wid] = v; smn[wid] = imin; smx[wid] = imax; }
    __syncthreads();
    if (t == 0) {
        #pragma unroll
        for (int w = 1; w < NT / 64; ++w) merge(sv[w], smn[w], smx[w], v, imin, imax);
        out[0] = (imin != imax) ? 1 : 0;
    }
}

extern "C" void kernel_launch(void* const* d_in, const int* in_sizes, int n_in,
                              void* d_out, int out_size, void* d_ws, size_t ws_size,
                              hipStream_t stream) {
    const float* x = (const float*)d_in[0];
    const int n  = in_sizes[0];      // 67108864
    const int n4 = n >> 2;
    Trip16* part = (Trip16*)d_ws;    // 2048 * 16 B = 32 KiB scratch

    argmax_part <<<NB, NT, 0, stream>>>((const f32x4*)x, part, n4);
    argmax_final<<<1,  NT, 0, stream>>>((const f32x4*)part, x, n4, n, (int*)d_out);
}

// Round 8
// 47.277 us; speedup vs baseline: 1.2012x; 1.2012x over previous
//
#include <hip/hip_runtime.h>
#include <math.h>

// Problem: x is (64, 1048576) f32 = 64M elements. Reference returns True
// iff argmax-with-lowest-index-ties != argmax-with-highest-index-ties, i.e.
// iff the global maximum value occurs at more than one index.
// Output dtype is bool -> harness reads d_out as int32. Store int 0/1.
//
// Journal: R2 two-kernel grid-stride float4 = 49.35us. R4 fused same-line
// atomics = 121us (serialized RMW tail ~20ns each). R5 4x pow2-strided
// unroll = 55.9us. R6 wave-shuffle reduce + 16B partials = 49.17us (best).
// R7 2xfloat4/thread + nt = 56.8us (32B inter-lane stride per load insn ->
// split transactions; nt effect confounded). R8 (this): exact R6 pattern
// (lane-dense stride-1 float4) + ONLY nontemporal_load — clean A/B on nt.

#define NB 2048   // blocks; 8 blocks/CU on 256 CUs = 32 waves/CU
#define NT 256    // threads per block (4 waves)

typedef float f32x4 __attribute__((ext_vector_type(4)));

struct Trip16 { float v; int imin; int imax; int pad; };  // 16B for dwordx4

__device__ __forceinline__ void upd(float x, int idx, float& v, int& imin, int& imax) {
    if (x > v)      { v = x; imin = idx; imax = idx; }
    else if (x == v){ if (idx < imin) imin = idx; if (idx > imax) imax = idx; }
}

__device__ __forceinline__ void merge(float bv, int bmn, int bmx,
                                      float& v, int& imin, int& imax) {
    if (bv > v)       { v = bv; imin = bmn; imax = bmx; }
    else if (bv == v) { if (bmn < imin) imin = bmn; if (bmx > imax) imax = bmx; }
}

// 64-lane butterfly reduce of (v, imin, imax) — register-only.
__device__ __forceinline__ void wave_reduce(float& v, int& imin, int& imax) {
    #pragma unroll
    for (int m = 32; m > 0; m >>= 1) {
        float ov = __shfl_xor(v, m, 64);
        int omn   = __shfl_xor(imin, m, 64);
        int omx   = __shfl_xor(imax, m, 64);
        merge(ov, omn, omx, v, imin, imax);
    }
}

__global__ __launch_bounds__(NT) void argmax_part(const f32x4* __restrict__ x,
                                                  Trip16* __restrict__ part, int n4) {
    const int tid = blockIdx.x * NT + threadIdx.x;
    const int stride = NB * NT;
    float v = -INFINITY; int imin = 0x7fffffff, imax = -1;
    for (int i = tid; i < n4; i += stride) {
        f32x4 f = __builtin_nontemporal_load(&x[i]);
        int b = i << 2;
        upd(f[0], b,     v, imin, imax);
        upd(f[1], b + 1, v, imin, imax);
        upd(f[2], b + 2, v, imin, imax);
        upd(f[3], b + 3, v, imin, imax);
    }

    wave_reduce(v, imin, imax);

    __shared__ float sv[NT / 64];
    __shared__ int   smn[NT / 64], smx[NT / 64];
    const int lane = threadIdx.x & 63;
    const int wid  = threadIdx.x >> 6;
    if (lane == 0) { sv[wid] = v; smn[wid] = imin; smx[wid] = imax; }
    __syncthreads();
    if (threadIdx.x == 0) {
        #pragma unroll
        for (int w = 1; w < NT / 64; ++w) merge(sv[w], smn[w], smx[w], v, imin, imax);
        f32x4 p;
        p[0] = v; p[1] = __int_as_float(imin); p[2] = __int_as_float(imax); p[3] = 0.0f;
        *reinterpret_cast<f32x4*>(&part[blockIdx.x]) = p;
    }
}

__global__ __launch_bounds__(NT) void argmax_final(const f32x4* __restrict__ part,
                                                   const float* __restrict__ x,
                                                   int n4, int n,
                                                   int* __restrict__ out) {
    const int t = threadIdx.x;
    float v = -INFINITY; int imin = 0x7fffffff, imax = -1;
    #pragma unroll
    for (int k = 0; k < NB / NT; ++k) {
        f32x4 p = part[t + k * NT];
        merge(p[0], __float_as_int(p[1]), __float_as_int(p[2]), v, imin, imax);
    }
    // Scalar tail (n not divisible by 4) — none for this shape, but be safe.
    for (int i = n4 * 4 + t; i < n; i += NT) upd(x[i], i, v, imin, imax);

    wave_reduce(v, imin, imax);

    __shared__ float sv[NT / 64];
    __shared__ int   smn[NT / 64], smx[NT / 64];
    const int lane = t & 63;
    const int wid  = t >> 6;
    if (lane == 0) { sv[wid] = v; smn[wid] = imin; smx[wid] = imax; }
    __syncthreads();
    if (t == 0) {
        #pragma unroll
        for (int w = 1; w < NT / 64; ++w) merge(sv[w], smn[w], smx[w], v, imin, imax);
        out[0] = (imin != imax) ? 1 : 0;
    }
}

extern "C" void kernel_launch(void* const* d_in, const int* in_sizes, int n_in,
                              void* d_out, int out_size, void* d_ws, size_t ws_size,
                              hipStream_t stream) {
    const float* x = (const float*)d_in[0];
    const int n  = in_sizes[0];      // 67108864
    const int n4 = n >> 2;
    Trip16* part = (Trip16*)d_ws;    // 2048 * 16 B = 32 KiB scratch

    argmax_part <<<NB, NT, 0, stream>>>((const f32x4*)x, part, n4);
    argmax_final<<<1,  NT, 0, stream>>>((const f32x4*)part, x, n4, n, (int*)d_out);
}